// Round 1
// baseline (370.896 us; speedup 1.0000x reference)
//
#include <hip/hip_runtime.h>

#define Cdim 64
#define INTER 32
#define Bn 4
#define Ln 4096
#define KTILE 64

// ---------------------------------------------------------------------------
// Kernel 1: channel projections. theta/phi/g stored as [b][l][INTER] rows.
// grid: Bn*(Ln/64) = 256 blocks, 64 threads; one (b,l) per thread.
// ---------------------------------------------------------------------------
__global__ void proj_kernel(const float* __restrict__ x,
                            const float* __restrict__ g_w, const float* __restrict__ g_b,
                            const float* __restrict__ th_w, const float* __restrict__ th_b,
                            const float* __restrict__ ph_w, const float* __restrict__ ph_b,
                            float* __restrict__ theta, float* __restrict__ phi,
                            float* __restrict__ g) {
    __shared__ float s_gw[INTER * Cdim], s_tw[INTER * Cdim], s_pw[INTER * Cdim];
    __shared__ float s_gb[INTER], s_tb[INTER], s_pb[INTER];
    int tid = threadIdx.x;
    for (int i = tid; i < INTER * Cdim; i += 64) {
        s_gw[i] = g_w[i];
        s_tw[i] = th_w[i];
        s_pw[i] = ph_w[i];
    }
    if (tid < INTER) {
        s_gb[tid] = g_b[tid];
        s_tb[tid] = th_b[tid];
        s_pb[tid] = ph_b[tid];
    }
    __syncthreads();

    int b = blockIdx.x / (Ln / 64);
    int l = (blockIdx.x % (Ln / 64)) * 64 + tid;

    float xr[Cdim];
    const float* xp = x + (size_t)b * Cdim * Ln + l;
#pragma unroll
    for (int c = 0; c < Cdim; c++) xr[c] = xp[(size_t)c * Ln];

    size_t rowoff = ((size_t)b * Ln + l) * INTER;
    for (int o = 0; o < INTER; o++) {
        float at = 0.f, ap = 0.f, ag = 0.f;
        const float* tw = &s_tw[o * Cdim];
        const float* pw = &s_pw[o * Cdim];
        const float* gw = &s_gw[o * Cdim];
#pragma unroll
        for (int c = 0; c < Cdim; c++) {
            at = fmaf(tw[c], xr[c], at);
            ap = fmaf(pw[c], xr[c], ap);
            ag = fmaf(gw[c], xr[c], ag);
        }
        theta[rowoff + o] = at + s_tb[o];
        phi[rowoff + o]   = ap + s_pb[o];
        g[rowoff + o]     = ag + s_gb[o];
    }
}

// ---------------------------------------------------------------------------
// Kernel 2: flash-attention partials. One query row per thread; keys split in
// kchunks chunks across blocks. Online softmax; partial (m, sum, acc[32]).
// grid: Bn * (Ln/256) * kchunks blocks, 256 threads.
// ---------------------------------------------------------------------------
__global__ void attn_kernel(const float* __restrict__ theta,
                            const float* __restrict__ phi,
                            const float* __restrict__ g,
                            float* __restrict__ part,
                            int kchunks, int keys_per_chunk) {
    __shared__ float s_phi[KTILE * INTER];  // 2048 floats
    __shared__ float s_g[KTILE * INTER];

    int tid = threadIdx.x;
    int idx = blockIdx.x;
    int b   = idx / (16 * kchunks);
    int rem = idx % (16 * kchunks);
    int qt  = rem / kchunks;
    int kc  = rem % kchunks;
    int l   = qt * 256 + tid;

    // load q row (32 floats, contiguous)
    float q[INTER];
    const float* qp = theta + ((size_t)b * Ln + l) * INTER;
#pragma unroll
    for (int j = 0; j < INTER; j += 4) {
        float4 v = *(const float4*)(qp + j);
        q[j] = v.x; q[j + 1] = v.y; q[j + 2] = v.z; q[j + 3] = v.w;
    }

    float m = -1e30f, ssum = 0.f;
    float acc[INTER];
#pragma unroll
    for (int j = 0; j < INTER; j++) acc[j] = 0.f;

    int k0 = kc * keys_per_chunk;
    for (int kt = 0; kt < keys_per_chunk; kt += KTILE) {
        __syncthreads();
        const float* pp = phi + ((size_t)b * Ln + (k0 + kt)) * INTER;
        const float* gp = g + ((size_t)b * Ln + (k0 + kt)) * INTER;
        // KTILE*INTER = 2048 floats = 512 float4 each; 256 threads -> 2 each
#pragma unroll
        for (int i = 0; i < 2; i++) {
            int e = tid + i * 256;
            ((float4*)s_phi)[e] = ((const float4*)pp)[e];
            ((float4*)s_g)[e]   = ((const float4*)gp)[e];
        }
        __syncthreads();

#pragma unroll 2
        for (int mm = 0; mm < KTILE; mm++) {
            const float* kp = &s_phi[mm * INTER];
            float s = 0.f;
#pragma unroll
            for (int j = 0; j < INTER; j++) s = fmaf(q[j], kp[j], s);
            float mn    = fmaxf(m, s);
            float alpha = __expf(m - mn);
            float p     = __expf(s - mn);
            ssum = ssum * alpha + p;
            m    = mn;
            const float* gv = &s_g[mm * INTER];
#pragma unroll
            for (int j = 0; j < INTER; j++) acc[j] = fmaf(acc[j], alpha, p * gv[j]);
        }
    }

    float* pout = part + (((size_t)b * Ln + l) * kchunks + kc) * 34;
    pout[0] = m;
    pout[1] = ssum;
#pragma unroll
    for (int j = 0; j < INTER; j++) pout[2 + j] = acc[j];
}

// ---------------------------------------------------------------------------
// Kernel 3: merge partial softmaxes, apply W projection + bias + residual.
// grid: Bn*Ln/256 = 64 blocks, 256 threads; one (b,l) per thread.
// ---------------------------------------------------------------------------
__global__ void merge_kernel(const float* __restrict__ part,
                             const float* __restrict__ x,
                             const float* __restrict__ W_w,
                             const float* __restrict__ W_b,
                             float* __restrict__ out, int kchunks) {
    __shared__ float s_w[Cdim * INTER];  // 2048 floats
    __shared__ float s_b[Cdim];
    int tid = threadIdx.x;
    for (int i = tid; i < Cdim * INTER; i += 256) s_w[i] = W_w[i];
    if (tid < Cdim) s_b[tid] = W_b[tid];
    __syncthreads();

    int gl = blockIdx.x * 256 + tid;
    int b = gl / Ln, l = gl % Ln;
    const float* pr = part + ((size_t)b * Ln + l) * (size_t)kchunks * 34;

    float M = -1e30f;
    for (int kcc = 0; kcc < kchunks; kcc++) M = fmaxf(M, pr[kcc * 34]);
    float S = 0.f;
    float y[INTER];
#pragma unroll
    for (int j = 0; j < INTER; j++) y[j] = 0.f;
    for (int kcc = 0; kcc < kchunks; kcc++) {
        float w = __expf(pr[kcc * 34] - M);
        S += pr[kcc * 34 + 1] * w;
#pragma unroll
        for (int j = 0; j < INTER; j++) y[j] = fmaf(pr[kcc * 34 + 2 + j], w, y[j]);
    }
    float inv = 1.f / S;
#pragma unroll
    for (int j = 0; j < INTER; j++) y[j] *= inv;

    const float* xp = x + (size_t)b * Cdim * Ln + l;
    float* op = out + (size_t)b * Cdim * Ln + l;
    for (int c = 0; c < Cdim; c++) {
        float a = s_b[c];
        const float* wr = &s_w[c * INTER];
#pragma unroll
        for (int j = 0; j < INTER; j++) a = fmaf(wr[j], y[j], a);
        op[(size_t)c * Ln] = a + xp[(size_t)c * Ln];
    }
}

extern "C" void kernel_launch(void* const* d_in, const int* in_sizes, int n_in,
                              void* d_out, int out_size, void* d_ws, size_t ws_size,
                              hipStream_t stream) {
    const float* x    = (const float*)d_in[0];
    const float* g_w  = (const float*)d_in[1];
    const float* g_b  = (const float*)d_in[2];
    const float* th_w = (const float*)d_in[3];
    const float* th_b = (const float*)d_in[4];
    const float* ph_w = (const float*)d_in[5];
    const float* ph_b = (const float*)d_in[6];
    const float* W_w  = (const float*)d_in[7];
    const float* W_b  = (const float*)d_in[8];
    float* out = (float*)d_out;

    float* wsf = (float*)d_ws;
    const size_t proj_elems = (size_t)Bn * Ln * INTER;  // 524288 floats each
    float* theta = wsf;
    float* phi   = wsf + proj_elems;
    float* g     = wsf + 2 * proj_elems;
    float* part  = wsf + 3 * proj_elems;

    int kchunks = 8;
    while (kchunks > 1 &&
           (3 * proj_elems + (size_t)Bn * Ln * kchunks * 34) * 4 > ws_size)
        kchunks >>= 1;

    proj_kernel<<<Bn * (Ln / 64), 64, 0, stream>>>(x, g_w, g_b, th_w, th_b,
                                                   ph_w, ph_b, theta, phi, g);
    attn_kernel<<<Bn * (Ln / 256) * kchunks, 256, 0, stream>>>(
        theta, phi, g, part, kchunks, Ln / kchunks);
    merge_kernel<<<Bn * Ln / 256, 256, 0, stream>>>(part, x, W_w, W_b, out,
                                                    kchunks);
}

// Round 2
// 151.238 us; speedup vs baseline: 2.4524x; 2.4524x over previous
//
#include <hip/hip_runtime.h>

#define Bn 4
#define Cdim 64
#define INTER 32
#define Ln 4096
#define LOG2E 1.44269504088896340736f

typedef _Float16 half_t;
typedef __attribute__((ext_vector_type(2))) _Float16 half2v;
typedef __attribute__((ext_vector_type(8))) _Float16 half8v;
typedef __attribute__((ext_vector_type(8))) short short8v;
typedef __attribute__((ext_vector_type(4))) float f32x4;

__device__ __forceinline__ unsigned short f2bf(float f) {
    unsigned u = __float_as_uint(f);
    u += 0x7fffu + ((u >> 16) & 1u);
    return (unsigned short)(u >> 16);
}
__device__ __forceinline__ float bf2f(unsigned short b) {
    return __uint_as_float(((unsigned)b) << 16);
}

// ---------------------------------------------------------------------------
// setup: Wcat f16[128][64] = [theta_w*log2e ; phi_w ; Wg=W_w*g_w],
//        biasbuf f32[128] = [th_b*log2e ; ph_b ; 0...], bc f32[64]=W_w*g_b+W_b
// ---------------------------------------------------------------------------
__global__ void setup_kernel(const float* __restrict__ g_w, const float* __restrict__ g_b,
                             const float* __restrict__ th_w, const float* __restrict__ th_b,
                             const float* __restrict__ ph_w, const float* __restrict__ ph_b,
                             const float* __restrict__ W_w, const float* __restrict__ W_b,
                             half_t* __restrict__ Wcat, float* __restrict__ biasbuf,
                             float* __restrict__ bc) {
    int tid = threadIdx.x;
    for (int i = tid; i < 128 * 64; i += 256) {
        int row = i >> 6, c2 = i & 63;
        float v;
        if (row < 32) v = th_w[row * 64 + c2] * LOG2E;
        else if (row < 64) v = ph_w[(row - 32) * 64 + c2];
        else {
            int cc = row - 64;
            v = 0.f;
            for (int j = 0; j < 32; j++) v = fmaf(W_w[cc * 32 + j], g_w[j * 64 + c2], v);
        }
        Wcat[i] = (half_t)v;
    }
    if (tid < 128) {
        float v = 0.f;
        if (tid < 32) v = th_b[tid] * LOG2E;
        else if (tid < 64) v = ph_b[tid - 32];
        biasbuf[tid] = v;
    }
    if (tid < 64) {
        float v = W_b[tid];
        for (int j = 0; j < 32; j++) v = fmaf(W_w[tid * 32 + j], g_b[j], v);
        bc[tid] = v;
    }
}

// ---------------------------------------------------------------------------
// proj: theta[b][l][32] f16 (scaled), phi[b][l][32] f16, gT[b][c=64][l] bf16
// grid 256 blocks x 256 thr; thread = (l within 64-tile, output-group of 32)
// ---------------------------------------------------------------------------
__global__ __launch_bounds__(256) void proj_kernel(
        const float* __restrict__ x, const half_t* __restrict__ Wcat,
        const float* __restrict__ biasbuf,
        half_t* __restrict__ theta, half_t* __restrict__ phi,
        unsigned short* __restrict__ gT) {
    __shared__ float4 sW[1024];     // 128 rows x 128B
    __shared__ float sbias[128];
    int tid = threadIdx.x;
    const float4* Wf4 = (const float4*)Wcat;
    for (int i = tid; i < 1024; i += 256) sW[i] = Wf4[i];
    if (tid < 128) sbias[tid] = biasbuf[tid];
    __syncthreads();

    int b = blockIdx.x >> 6;
    int l = ((blockIdx.x & 63) << 6) + (tid & 63);
    int grp = tid >> 6;

    float xr[64];
#pragma unroll
    for (int c = 0; c < 64; c++) xr[c] = x[((size_t)(b * 64 + c)) * Ln + l];
    half2v xh[32];
#pragma unroll
    for (int j = 0; j < 32; j++) {
        half2v h; h.x = (half_t)xr[2 * j]; h.y = (half_t)xr[2 * j + 1];
        xh[j] = h;
    }

    int baserow = grp * 32;
    half_t hv[32];
#pragma unroll 4
    for (int o = 0; o < 32; o++) {
        int row = baserow + o;
        const float4* wr = &sW[row * 8];
        float acc = sbias[row];
#pragma unroll
        for (int i = 0; i < 8; i++) {
            float4 w4 = wr[i];
            const half2v* wp = (const half2v*)&w4;
#pragma unroll
            for (int j = 0; j < 4; j++)
                acc = __builtin_amdgcn_fdot2(wp[j], xh[i * 4 + j], acc, false);
        }
        if (grp >= 2) {
            gT[((size_t)(b * 64 + (grp - 2) * 32 + o)) * Ln + l] = f2bf(acc);
        } else {
            hv[o] = (half_t)acc;
        }
    }
    if (grp == 0) {
        float4* dst = (float4*)(theta + ((size_t)(b * Ln + l)) * 32);
        const float4* src = (const float4*)hv;
#pragma unroll
        for (int i = 0; i < 4; i++) dst[i] = src[i];
    } else if (grp == 1) {
        float4* dst = (float4*)(phi + ((size_t)(b * Ln + l)) * 32);
        const float4* src = (const float4*)hv;
#pragma unroll
        for (int i = 0; i < 4; i++) dst[i] = src[i];
    }
}

// ---------------------------------------------------------------------------
// attn: MFMA flash attention, no-max online softmax (exp2, summable partials).
// Wave = 32 q-rows; block = 4 waves = 128 q-rows. Grid = Bn * 32 * KC.
// part[b][kc][c=64][l] bf16 (y_chunk), Sden[b][kc][l] f32 (l_chunk).
// ---------------------------------------------------------------------------
__global__ __launch_bounds__(256, 2) void attn_kernel(
        const half_t* __restrict__ theta, const half_t* __restrict__ phi,
        const unsigned short* __restrict__ gT,
        unsigned short* __restrict__ part, float* __restrict__ Sden,
        int KC, int CH) {
    __shared__ unsigned short pbuf[4][2][16][72];  // wave, qf, row(q), col(k)+pad

    int tid = threadIdx.x;
    int lane = tid & 63, widx = tid >> 6;
    int l15 = lane & 15, quad = lane >> 4;

    int blk = blockIdx.x;
    int b = blk / (32 * KC);
    int rem = blk % (32 * KC);
    int qblk = rem / KC;
    int kc = rem % KC;
    int qbase = qblk * 128 + widx * 32;
    int k0 = kc * CH;

    // theta A-fragments (2 x 16 q-rows), persistent
    half8v a0 = *(const half8v*)(theta + ((size_t)(b * Ln + qbase + l15)) * 32 + quad * 8);
    half8v a1 = *(const half8v*)(theta + ((size_t)(b * Ln + qbase + 16 + l15)) * 32 + quad * 8);

    f32x4 acc[2][4];
    float lsum[2][4];
#pragma unroll
    for (int qf = 0; qf < 2; qf++)
#pragma unroll
        for (int cf = 0; cf < 4; cf++) { acc[qf][cf] = (f32x4){0.f, 0.f, 0.f, 0.f}; }
#pragma unroll
    for (int qf = 0; qf < 2; qf++)
#pragma unroll
        for (int r = 0; r < 4; r++) lsum[qf][r] = 0.f;

    const half_t* phib = phi + (size_t)b * Ln * 32;
    const unsigned short* gTb = gT + (size_t)b * Cdim * Ln;

    // prefetch first phi frags
    half8v bf_c[4];
#pragma unroll
    for (int kf = 0; kf < 4; kf++)
        bf_c[kf] = *(const half8v*)(phib + ((size_t)(k0 + kf * 16 + l15)) * 32 + quad * 8);

    for (int kt = k0; kt < k0 + CH; kt += 64) {
        // prefetch g'' fragments for both 32-key halves (independent of S path)
        short8v gf[2][4];
#pragma unroll
        for (int kg = 0; kg < 2; kg++)
#pragma unroll
            for (int cf = 0; cf < 4; cf++)
                gf[kg][cf] = *(const short8v*)(gTb + ((size_t)(cf * 16 + l15)) * Ln +
                                               kt + kg * 32 + quad * 8);
        // prefetch next phi frags
        half8v bf_n[4];
        if (kt + 64 < k0 + CH) {
#pragma unroll
            for (int kf = 0; kf < 4; kf++)
                bf_n[kf] = *(const half8v*)(phib + ((size_t)(kt + 64 + kf * 16 + l15)) * 32 +
                                            quad * 8);
        }

        // S = theta * phi^T  (rows=q, cols=key)
        f32x4 s[2][4];
        f32x4 z = {0.f, 0.f, 0.f, 0.f};
#pragma unroll
        for (int kf = 0; kf < 4; kf++) {
            s[0][kf] = __builtin_amdgcn_mfma_f32_16x16x32_f16(a0, bf_c[kf], z, 0, 0, 0);
            s[1][kf] = __builtin_amdgcn_mfma_f32_16x16x32_f16(a1, bf_c[kf], z, 0, 0, 0);
        }

        // p = exp2(s), accumulate denominator, write P tile (bf16) to LDS
#pragma unroll
        for (int qf = 0; qf < 2; qf++)
#pragma unroll
            for (int kf = 0; kf < 4; kf++)
#pragma unroll
                for (int r = 0; r < 4; r++) {
                    float p = __builtin_amdgcn_exp2f(fminf(s[qf][kf][r], 100.f));
                    lsum[qf][r] += p;
                    pbuf[widx][qf][quad * 4 + r][kf * 16 + l15] = f2bf(p);
                }

        // PV: y += P * g''^T   (P A-frags from LDS, g'' B-frags)
#pragma unroll
        for (int kg = 0; kg < 2; kg++) {
            short8v pa[2];
#pragma unroll
            for (int qf = 0; qf < 2; qf++)
                pa[qf] = *(const short8v*)&pbuf[widx][qf][l15][kg * 32 + quad * 8];
#pragma unroll
            for (int qf = 0; qf < 2; qf++)
#pragma unroll
                for (int cf = 0; cf < 4; cf++)
                    acc[qf][cf] = __builtin_amdgcn_mfma_f32_16x16x32_bf16(
                        pa[qf], gf[kg][cf], acc[qf][cf], 0, 0, 0);
        }

#pragma unroll
        for (int kf = 0; kf < 4; kf++) bf_c[kf] = bf_n[kf];
    }

    // reduce lsum across the 16 lanes (cols) of each quad-group
#pragma unroll
    for (int qf = 0; qf < 2; qf++)
#pragma unroll
        for (int r = 0; r < 4; r++) {
            float v = lsum[qf][r];
            v += __shfl_xor(v, 1, 16);
            v += __shfl_xor(v, 2, 16);
            v += __shfl_xor(v, 4, 16);
            v += __shfl_xor(v, 8, 16);
            lsum[qf][r] = v;
        }

    // y_chunk = acc / l_chunk -> bf16; store part + Sden
    size_t pbase = ((size_t)(b * KC + kc)) * Cdim * Ln;
#pragma unroll
    for (int qf = 0; qf < 2; qf++) {
        float inv[4];
#pragma unroll
        for (int r = 0; r < 4; r++) inv[r] = 1.f / (lsum[qf][r] + 1e-37f);
#pragma unroll
        for (int cf = 0; cf < 4; cf++)
#pragma unroll
            for (int r = 0; r < 4; r++) {
                int q = qbase + qf * 16 + quad * 4 + r;
                int c = cf * 16 + l15;
                part[pbase + (size_t)c * Ln + q] = f2bf(acc[qf][cf][r] * inv[r]);
            }
        if (l15 == 0) {
#pragma unroll
            for (int r = 0; r < 4; r++) {
                int q = qbase + qf * 16 + quad * 4 + r;
                Sden[((size_t)(b * KC + kc)) * Ln + q] = lsum[qf][r];
            }
        }
    }
}

// ---------------------------------------------------------------------------
// merge: out[b][c][l] = sum_kc(y_kc * l_kc)/sum_kc(l_kc) + bc[c] + x[b][c][l]
// ---------------------------------------------------------------------------
__global__ __launch_bounds__(256) void merge_kernel(
        const unsigned short* __restrict__ part, const float* __restrict__ Sden,
        const float* __restrict__ bc, const float* __restrict__ x,
        float* __restrict__ out, int KC) {
    int idx = blockIdx.x * 256 + threadIdx.x;
    int l = idx & (Ln - 1);
    int c = (idx >> 12) & 63;
    int b = idx >> 18;
    float num = 0.f, den = 0.f;
    for (int kc = 0; kc < KC; kc++) {
        float lc = Sden[((size_t)(b * KC + kc)) * Ln + l];
        float yc = bf2f(part[((size_t)(b * KC + kc)) * Cdim * Ln + (size_t)c * Ln + l]);
        num = fmaf(yc, lc, num);
        den += lc;
    }
    out[idx] = num / den + bc[c] + x[idx];
}

extern "C" void kernel_launch(void* const* d_in, const int* in_sizes, int n_in,
                              void* d_out, int out_size, void* d_ws, size_t ws_size,
                              hipStream_t stream) {
    const float* x    = (const float*)d_in[0];
    const float* g_w  = (const float*)d_in[1];
    const float* g_b  = (const float*)d_in[2];
    const float* th_w = (const float*)d_in[3];
    const float* th_b = (const float*)d_in[4];
    const float* ph_w = (const float*)d_in[5];
    const float* ph_b = (const float*)d_in[6];
    const float* W_w  = (const float*)d_in[7];
    const float* W_b  = (const float*)d_in[8];
    float* out = (float*)d_out;

    char* w = (char*)d_ws;
    const size_t off_theta = 0;
    const size_t off_phi   = 1048576;           // 4*4096*32*2
    const size_t off_gT    = 2097152;           // 4*64*4096*2
    const size_t off_Wcat  = 4194304;           // 128*64*2
    const size_t off_bias  = 4210688;           // 128*4
    const size_t off_bc    = 4211200;           // 64*4
    const size_t off_Sden  = 4211456;

    // pick largest key-chunk count that fits the workspace
    int KC = 4;
    while (KC > 1) {
        size_t need = off_Sden + (size_t)KC * (4 * Ln * 4)            // Sden
                      + (size_t)KC * (4ull * Cdim * Ln * 2);          // part
        if (need <= ws_size) break;
        KC >>= 1;
    }
    size_t off_part = off_Sden + (size_t)KC * (4 * Ln * 4);
    // align part to 256B
    off_part = (off_part + 255) & ~(size_t)255;

    half_t* theta = (half_t*)(w + off_theta);
    half_t* phi   = (half_t*)(w + off_phi);
    unsigned short* gT = (unsigned short*)(w + off_gT);
    half_t* Wcat  = (half_t*)(w + off_Wcat);
    float* biasbuf = (float*)(w + off_bias);
    float* bc     = (float*)(w + off_bc);
    float* Sden   = (float*)(w + off_Sden);
    unsigned short* part = (unsigned short*)(w + off_part);

    int CH = Ln / KC;

    setup_kernel<<<1, 256, 0, stream>>>(g_w, g_b, th_w, th_b, ph_w, ph_b, W_w, W_b,
                                        Wcat, biasbuf, bc);
    proj_kernel<<<Bn * 64, 256, 0, stream>>>(x, Wcat, biasbuf, theta, phi, gT);
    attn_kernel<<<Bn * 32 * KC, 256, 0, stream>>>(theta, phi, gT, part, Sden, KC, CH);
    merge_kernel<<<Bn * Cdim * Ln / 256, 256, 0, stream>>>(part, Sden, bc, x, out, KC);
}

// Round 3
// 137.799 us; speedup vs baseline: 2.6916x; 1.0975x over previous
//
#include <hip/hip_runtime.h>

#define Bn 4
#define Cdim 64
#define INTER 32
#define Ln 4096
#define LOG2E 1.44269504088896340736f

typedef _Float16 half_t;
typedef __attribute__((ext_vector_type(2))) _Float16 half2v;
typedef __attribute__((ext_vector_type(4))) _Float16 half4v;
typedef __attribute__((ext_vector_type(8))) _Float16 half8v;
typedef __attribute__((ext_vector_type(8))) short short8v;
typedef __attribute__((ext_vector_type(4))) float f32x4;

__device__ __forceinline__ unsigned short f2bf(float f) {
    unsigned u = __float_as_uint(f);
    u += 0x7fffu + ((u >> 16) & 1u);
    return (unsigned short)(u >> 16);
}
__device__ __forceinline__ float bf2f(unsigned short b) {
    return __uint_as_float(((unsigned)b) << 16);
}
// pack bf16(a) into low16, bf16(b) into high16 (round-half-up, 3 VALU ops)
__device__ __forceinline__ unsigned pack_bf(float a, float b) {
    unsigned ua = __float_as_uint(a) + 0x8000u;
    unsigned ub = __float_as_uint(b) + 0x8000u;
    return __builtin_amdgcn_perm(ub, ua, 0x07060302);
}

// ---------------------------------------------------------------------------
// setup (parallel): Wcat f16[128][64] = [th_w*log2e ; ph_w ; W_w*g_w],
// biasbuf f32[128] = [th_b*log2e ; ph_b ; 0], bc f32[64] = W_w*g_b + W_b
// ---------------------------------------------------------------------------
__global__ void setup_kernel(const float* __restrict__ g_w, const float* __restrict__ g_b,
                             const float* __restrict__ th_w, const float* __restrict__ th_b,
                             const float* __restrict__ ph_w, const float* __restrict__ ph_b,
                             const float* __restrict__ W_w, const float* __restrict__ W_b,
                             half_t* __restrict__ Wcat, float* __restrict__ biasbuf,
                             float* __restrict__ bc) {
    int blk = blockIdx.x, tid = threadIdx.x;
    if (blk < 128) {
        int row = blk, c = tid;
        float v;
        if (row < 32) v = th_w[row * 64 + c] * LOG2E;
        else if (row < 64) v = ph_w[(row - 32) * 64 + c];
        else {
            int cc = row - 64;
            v = 0.f;
            for (int j = 0; j < 32; j++) v = fmaf(W_w[cc * 32 + j], g_w[j * 64 + c], v);
        }
        Wcat[row * 64 + c] = (half_t)v;
    } else if (blk == 128) {
        float v0 = (tid < 32) ? th_b[tid] * LOG2E : ph_b[tid - 32];
        biasbuf[tid] = v0;
        biasbuf[64 + tid] = 0.f;
    } else {
        float v = W_b[tid];
        for (int j = 0; j < 32; j++) v = fmaf(W_w[tid * 32 + j], g_b[j], v);
        bc[tid] = v;
    }
}

// ---------------------------------------------------------------------------
// proj: theta/phi f16 [b][l][32], gT bf16 [b][c=64][l]. x staged once in LDS.
// grid Bn*64 blocks x 256 thr. wave = one grp (uniform sW broadcast reads).
// ---------------------------------------------------------------------------
__global__ __launch_bounds__(256) void proj_kernel(
        const float* __restrict__ x, const half_t* __restrict__ Wcat,
        const float* __restrict__ biasbuf,
        half_t* __restrict__ theta, half_t* __restrict__ phi,
        unsigned short* __restrict__ gT) {
    __shared__ float4 sW[1024];          // 128 rows x 128B
    __shared__ float sbias[128];
    __shared__ half_t sx[64][76];        // [l][c], pad 76 (152B rows, 8B aligned)
    int tid = threadIdx.x;
    const float4* Wf4 = (const float4*)Wcat;
    for (int i = tid; i < 1024; i += 256) sW[i] = Wf4[i];
    if (tid < 128) sbias[tid] = biasbuf[tid];

    int b = blockIdx.x >> 6;
    int l0 = (blockIdx.x & 63) << 6;
#pragma unroll
    for (int p = 0; p < 4; p++) {
        int idx = tid + p * 256;          // 0..1023
        int c = idx >> 4;                 // 0..63
        int lq = (idx & 15) << 2;         // 0..60
        float4 v = *(const float4*)&x[((size_t)(b * 64 + c)) * Ln + l0 + lq];
        sx[lq + 0][c] = (half_t)v.x;
        sx[lq + 1][c] = (half_t)v.y;
        sx[lq + 2][c] = (half_t)v.z;
        sx[lq + 3][c] = (half_t)v.w;
    }
    __syncthreads();

    int l = tid & 63;
    int grp = tid >> 6;

    half2v xh[32];
#pragma unroll
    for (int k = 0; k < 16; k++) {
        half4v h4 = *(const half4v*)&sx[l][4 * k];
        half2v a; a.x = h4.x; a.y = h4.y;
        half2v bb; bb.x = h4.z; bb.y = h4.w;
        xh[2 * k] = a;
        xh[2 * k + 1] = bb;
    }

    int gl = l0 + l;
    int baserow = grp * 32;
    half_t hv[32];
#pragma unroll 4
    for (int o = 0; o < 32; o++) {
        int row = baserow + o;
        const float4* wr = &sW[row * 8];
        float acc = sbias[row];
#pragma unroll
        for (int i = 0; i < 8; i++) {
            float4 w4 = wr[i];
            const half2v* wp = (const half2v*)&w4;
#pragma unroll
            for (int j = 0; j < 4; j++)
                acc = __builtin_amdgcn_fdot2(wp[j], xh[i * 4 + j], acc, false);
        }
        if (grp >= 2) {
            gT[((size_t)(b * 64 + (grp - 2) * 32 + o)) * Ln + gl] = f2bf(acc);
        } else {
            hv[o] = (half_t)acc;
        }
    }
    if (grp == 0) {
        float4* dst = (float4*)(theta + ((size_t)(b * Ln + gl)) * 32);
        const float4* src = (const float4*)hv;
#pragma unroll
        for (int i = 0; i < 4; i++) dst[i] = src[i];
    } else if (grp == 1) {
        float4* dst = (float4*)(phi + ((size_t)(b * Ln + gl)) * 32);
        const float4* src = (const float4*)hv;
#pragma unroll
        for (int i = 0; i < 4; i++) dst[i] = src[i];
    }
}

// ---------------------------------------------------------------------------
// attn: S' = phi * theta^T (keys = rows) so the S-fragment holds 4 consecutive
// keys per lane -> paired bf16 pack + ds_write_b64; denominator is a plain
// per-lane accumulator. Partials stored UNNORMALIZED: part = sum_chunk(p*g),
// Sden = sum_chunk(p). No barriers in the K-loop (per-wave LDS buffer).
// ---------------------------------------------------------------------------
__global__ __launch_bounds__(256, 4) void attn_kernel(
        const half_t* __restrict__ theta, const half_t* __restrict__ phi,
        const unsigned short* __restrict__ gT,
        unsigned short* __restrict__ part, float* __restrict__ Sden,
        int KC, int CH) {
    __shared__ unsigned short pbuf[4][2][16][72];  // [wave][qf][q=16][k=64+pad]

    int tid = threadIdx.x;
    int lane = tid & 63, widx = tid >> 6;
    int l15 = lane & 15, quad = lane >> 4;

    int blk = blockIdx.x;
    int b = blk / (32 * KC);
    int rem = blk % (32 * KC);
    int qblk = rem / KC;
    int kc = rem % KC;
    int qbase = qblk * 128 + widx * 32;
    int k0 = kc * CH;

    // theta B-fragments (n = q), persistent
    half8v th[2];
#pragma unroll
    for (int qf = 0; qf < 2; qf++)
        th[qf] = *(const half8v*)(theta + ((size_t)(b * Ln + qbase + qf * 16 + l15)) * 32 +
                                  quad * 8);

    f32x4 acc[2][4];
#pragma unroll
    for (int qf = 0; qf < 2; qf++)
#pragma unroll
        for (int cf = 0; cf < 4; cf++) acc[qf][cf] = (f32x4){0.f, 0.f, 0.f, 0.f};
    float lsum[2] = {0.f, 0.f};

    const half_t* phib = phi + (size_t)b * Ln * 32;
    const unsigned short* gTb = gT + (size_t)b * Cdim * Ln;
    const f32x4 z = {0.f, 0.f, 0.f, 0.f};

    for (int kt = k0; kt < k0 + CH; kt += 64) {
        // g'' B-frags (n = c) for both 32-key halves
        short8v gf[2][4];
#pragma unroll
        for (int kg = 0; kg < 2; kg++)
#pragma unroll
            for (int cf = 0; cf < 4; cf++)
                gf[kg][cf] = *(const short8v*)(gTb + ((size_t)(cf * 16 + l15)) * Ln +
                                               kt + kg * 32 + quad * 8);
        // phi A-frags (m = keys)
        half8v ph[4];
#pragma unroll
        for (int kf = 0; kf < 4; kf++)
            ph[kf] = *(const half8v*)(phib + ((size_t)(kt + kf * 16 + l15)) * 32 + quad * 8);

        // S' = phi * theta^T ; p = exp2(s); write P tile (paired bf16)
#pragma unroll
        for (int kf = 0; kf < 4; kf++) {
#pragma unroll
            for (int qf = 0; qf < 2; qf++) {
                f32x4 s = __builtin_amdgcn_mfma_f32_16x16x32_f16(ph[kf], th[qf], z, 0, 0, 0);
                float p0 = __builtin_amdgcn_exp2f(s[0]);
                float p1 = __builtin_amdgcn_exp2f(s[1]);
                float p2 = __builtin_amdgcn_exp2f(s[2]);
                float p3 = __builtin_amdgcn_exp2f(s[3]);
                lsum[qf] += (p0 + p1) + (p2 + p3);
                uint2 w;
                w.x = pack_bf(p0, p1);
                w.y = pack_bf(p2, p3);
                *(uint2*)&pbuf[widx][qf][l15][kf * 16 + quad * 4] = w;
            }
        }

        // PV: y += P * g''^T (A-frags from per-wave LDS, no barrier needed)
#pragma unroll
        for (int kg = 0; kg < 2; kg++) {
            short8v pa[2];
#pragma unroll
            for (int qf = 0; qf < 2; qf++)
                pa[qf] = *(const short8v*)&pbuf[widx][qf][l15][kg * 32 + quad * 8];
#pragma unroll
            for (int qf = 0; qf < 2; qf++)
#pragma unroll
                for (int cf = 0; cf < 4; cf++)
                    acc[qf][cf] = __builtin_amdgcn_mfma_f32_16x16x32_bf16(
                        pa[qf], gf[kg][cf], acc[qf][cf], 0, 0, 0);
        }
    }

    // full denominator: reduce across quads (all lanes end with q = l15 total)
#pragma unroll
    for (int qf = 0; qf < 2; qf++) {
        float v = lsum[qf];
        v += __shfl_xor(v, 16);
        v += __shfl_xor(v, 32);
        lsum[qf] = v;
    }
    size_t sbase = ((size_t)(b * KC + kc)) * Ln + qbase;
    if (lane < 16) {
        Sden[sbase + lane] = lsum[0];
        Sden[sbase + 16 + lane] = lsum[1];
    }

    // transpose acc (raw, unnormalized) through per-wave LDS -> coalesced store
    unsigned short* pT = (unsigned short*)&pbuf[widx][0][0][0];  // 2304 u16
#pragma unroll
    for (int qf = 0; qf < 2; qf++)
#pragma unroll
        for (int cf = 0; cf < 4; cf++) {
            int c = cf * 16 + l15;
            *(unsigned*)&pT[c * 36 + qf * 16 + quad * 4] =
                pack_bf(acc[qf][cf][0], acc[qf][cf][1]);
            *(unsigned*)&pT[c * 36 + qf * 16 + quad * 4 + 2] =
                pack_bf(acc[qf][cf][2], acc[qf][cf][3]);
        }
    size_t pbase = ((size_t)(b * KC + kc)) * Cdim * Ln;
    const unsigned short* src = pT + lane * 36;
    unsigned short* dst = part + pbase + (size_t)lane * Ln + qbase;
#pragma unroll
    for (int j = 0; j < 8; j++) {
        uint2 v = *(const uint2*)&src[j * 4];
        *(uint2*)&dst[j * 4] = v;
    }
}

// ---------------------------------------------------------------------------
// merge: out = sum_kc(part)/sum_kc(Sden) + bc[c] + x ; 4 l's per thread
// ---------------------------------------------------------------------------
__global__ __launch_bounds__(256) void merge_kernel(
        const unsigned short* __restrict__ part, const float* __restrict__ Sden,
        const float* __restrict__ bc, const float* __restrict__ x,
        float* __restrict__ out, int KC) {
    int t = blockIdx.x * 256 + threadIdx.x;
    int l4 = (t & 1023) << 2;
    int c = (t >> 10) & 63;
    int b = t >> 16;
    float4 num = {0.f, 0.f, 0.f, 0.f};
    float4 den = {0.f, 0.f, 0.f, 0.f};
    for (int kc = 0; kc < KC; kc++) {
        const unsigned short* pp =
            part + ((size_t)(b * KC + kc)) * Cdim * Ln + (size_t)c * Ln + l4;
        ushort4 y4 = *(const ushort4*)pp;
        float4 lc = *(const float4*)&Sden[((size_t)(b * KC + kc)) * Ln + l4];
        num.x += bf2f(y4.x); num.y += bf2f(y4.y);
        num.z += bf2f(y4.z); num.w += bf2f(y4.w);
        den.x += lc.x; den.y += lc.y; den.z += lc.z; den.w += lc.w;
    }
    float bias = bc[c];
    size_t xi = (size_t)t * 4;
    float4 xv = *(const float4*)&x[xi];
    float4 o;
    o.x = num.x / den.x + bias + xv.x;
    o.y = num.y / den.y + bias + xv.y;
    o.z = num.z / den.z + bias + xv.z;
    o.w = num.w / den.w + bias + xv.w;
    *(float4*)&out[xi] = o;
}

extern "C" void kernel_launch(void* const* d_in, const int* in_sizes, int n_in,
                              void* d_out, int out_size, void* d_ws, size_t ws_size,
                              hipStream_t stream) {
    const float* x    = (const float*)d_in[0];
    const float* g_w  = (const float*)d_in[1];
    const float* g_b  = (const float*)d_in[2];
    const float* th_w = (const float*)d_in[3];
    const float* th_b = (const float*)d_in[4];
    const float* ph_w = (const float*)d_in[5];
    const float* ph_b = (const float*)d_in[6];
    const float* W_w  = (const float*)d_in[7];
    const float* W_b  = (const float*)d_in[8];
    float* out = (float*)d_out;

    char* w = (char*)d_ws;
    const size_t off_theta = 0;
    const size_t off_phi   = 1048576;           // 4*4096*32*2
    const size_t off_gT    = 2097152;           // 4*64*4096*2
    const size_t off_Wcat  = 4194304;           // 128*64*2
    const size_t off_bias  = 4210688;           // 128*4
    const size_t off_bc    = 4211200;           // 64*4
    const size_t off_Sden  = 4211456;           // 16B aligned

    int KC = 8;
    size_t off_part = 0;
    while (true) {
        off_part = off_Sden + (size_t)KC * (Bn * Ln * 4);
        off_part = (off_part + 255) & ~(size_t)255;
        size_t need = off_part + (size_t)KC * ((size_t)Bn * Cdim * Ln * 2);
        if (need <= ws_size || KC == 1) break;
        KC >>= 1;
    }

    half_t* theta = (half_t*)(w + off_theta);
    half_t* phi   = (half_t*)(w + off_phi);
    unsigned short* gT = (unsigned short*)(w + off_gT);
    half_t* Wcat  = (half_t*)(w + off_Wcat);
    float* biasbuf = (float*)(w + off_bias);
    float* bc     = (float*)(w + off_bc);
    float* Sden   = (float*)(w + off_Sden);
    unsigned short* part = (unsigned short*)(w + off_part);

    int CH = Ln / KC;

    setup_kernel<<<130, 64, 0, stream>>>(g_w, g_b, th_w, th_b, ph_w, ph_b, W_w, W_b,
                                         Wcat, biasbuf, bc);
    proj_kernel<<<Bn * 64, 256, 0, stream>>>(x, Wcat, biasbuf, theta, phi, gT);
    attn_kernel<<<Bn * 32 * KC, 256, 0, stream>>>(theta, phi, gT, part, Sden, KC, CH);
    merge_kernel<<<Bn * Cdim * Ln / 1024, 256, 0, stream>>>(part, Sden, bc, x, out, KC);
}